// Round 16
// baseline (357.463 us; speedup 1.0000x reference)
//
#include <hip/hip_runtime.h>
#include <hip/hip_bf16.h>

typedef unsigned short u16;
typedef __attribute__((ext_vector_type(8))) short short8;
typedef __attribute__((ext_vector_type(8))) unsigned short u16x8;
typedef __attribute__((ext_vector_type(4))) float f32x4;

#define H_DIM 2048
#define EI_DIM 1024
#define NEXP 8

template <int V> struct IC { static constexpr int value = V; };

__device__ __forceinline__ u16 f2bf(float f) {
  __hip_bfloat16 h = __float2bfloat16(f);
  return __builtin_bit_cast(unsigned short, h);
}

__device__ __forceinline__ void load_lds16(const void* g, void* lds) {
  __builtin_amdgcn_global_load_lds(
      (const __attribute__((address_space(1))) unsigned int*)g,
      (__attribute__((address_space(3))) unsigned int*)lds, 16, 0, 0);
}

// ---------------- fused routing: hist + scan + rank in one block ----------------
__global__ __launch_bounds__(1024) void route_kernel(const int* __restrict__ pid,
                                                     int* __restrict__ offcnt,
                                                     int* __restrict__ order, int T) {
  __shared__ int hist[2048];
  __shared__ int lds[256];
  __shared__ int basel[2048];
  int tid = threadIdx.x, w = tid >> 6, lane = tid & 63;
  unsigned long long below = (1ull << lane) - 1ull;
#pragma unroll 1
  for (int i = 0; i < 16; ++i) {
    int seg = w * 16 + i;
    int eid = pid[seg * 64 + lane] & 7;
#pragma unroll
    for (int e = 0; e < NEXP; ++e) {
      unsigned long long m = __ballot(eid == e);
      if (lane == 0) hist[e * 256 + seg] = __popcll(m);
    }
  }
  __syncthreads();
  int v[8], s = 0;
  if (tid < 256) {
#pragma unroll
    for (int j = 0; j < 8; ++j) { v[j] = hist[tid * 8 + j]; s += v[j]; }
    lds[tid] = s;
  }
  __syncthreads();
  for (int d = 1; d < 256; d <<= 1) {
    int t = (tid < 256 && tid >= d) ? lds[tid - d] : 0;
    __syncthreads();
    if (tid < 256) lds[tid] += t;
    __syncthreads();
  }
  if (tid < 256) {
    int run = lds[tid] - s;
#pragma unroll
    for (int j = 0; j < 8; ++j) { basel[tid * 8 + j] = run; run += v[j]; }
  }
  __syncthreads();
  if (tid < NEXP) {
    int o = basel[tid * 256];
    int nx = (tid < NEXP - 1) ? basel[(tid + 1) * 256] : T;
    offcnt[tid] = o;
    offcnt[8 + tid] = nx - o;
  }
#pragma unroll 1
  for (int i = 0; i < 16; ++i) {
    int seg = w * 16 + i;
    int t = seg * 64 + lane;
    int eid = pid[t] & 7;
#pragma unroll
    for (int e = 0; e < NEXP; ++e) {
      unsigned long long m = __ballot(eid == e);
      if (eid == e) order[basel[e * 256 + seg] + __popcll(m & below)] = t;
    }
  }
}

// ---------------- fused convert: both weight transposes + x gather ----------------
__device__ __forceinline__ void transpose_tile(const float* __restrict__ in,
                                               u16* __restrict__ out, int R, int C, int bx) {
  __shared__ u16 tile[64][65];
  int nbr = R >> 6;
  int per_e = nbr * (C >> 6);
  int e = bx / per_e, rem = bx % per_e;
  int tr = rem % nbr, tc = rem / nbr;
  const float* ine = in + (size_t)e * R * C;
  u16* oute = out + (size_t)e * R * C;
  int r0 = tr * 64, c0 = tc * 64;
  int tid = threadIdx.x;
  int lrow = tid >> 4, lc4 = (tid & 15) * 4;
#pragma unroll
  for (int p = 0; p < 4; ++p) {
    int rl = p * 16 + lrow;
    float4 v = *(const float4*)&ine[(size_t)(r0 + rl) * C + c0 + lc4];
    tile[rl][lc4 + 0] = f2bf(v.x);
    tile[rl][lc4 + 1] = f2bf(v.y);
    tile[rl][lc4 + 2] = f2bf(v.z);
    tile[rl][lc4 + 3] = f2bf(v.w);
  }
  __syncthreads();
#pragma unroll
  for (int p = 0; p < 2; ++p) {
    int idx = p * 256 + tid;
    int jr = idx >> 3, hg = (idx & 7) * 8;
    u16x8 v;
#pragma unroll
    for (int i = 0; i < 8; ++i) v[i] = tile[hg + i][jr];
    *(u16x8*)&oute[(size_t)(c0 + jr) * R + r0 + hg] = v;
  }
}

__global__ __launch_bounds__(256) void convert_kernel(
    const float* __restrict__ gup, const float* __restrict__ dwn, const float* __restrict__ x,
    const int* __restrict__ order, u16* __restrict__ wguT, u16* __restrict__ wdT,
    u16* __restrict__ xg) {
  int bx = blockIdx.x;
  if (bx < 8192) {
    transpose_tile(gup, wguT, 2048, 2048, bx);
  } else if (bx < 8192 + 4096) {
    transpose_tile(dwn, wdT, 1024, 2048, bx - 8192);
  } else {
    int g0 = (bx - 12288) * 8;
    int c = threadIdx.x * 8;
#pragma unroll 1
    for (int r = 0; r < 8; ++r) {
      int g = g0 + r;
      int t = order[g];
      const float* src = x + (size_t)t * H_DIM;
      u16* dst = xg + (size_t)g * H_DIM;
      float4 a = *(const float4*)&src[c];
      float4 b = *(const float4*)&src[c + 4];
      u16x8 vv;
      vv[0] = f2bf(a.x); vv[1] = f2bf(a.y); vv[2] = f2bf(a.z); vv[3] = f2bf(a.w);
      vv[4] = f2bf(b.x); vv[5] = f2bf(b.y); vv[6] = f2bf(b.z); vv[7] = f2bf(b.w);
      *(u16x8*)&dst[c] = vv;
    }
  }
}

// ---------------- 256x256 GEMM, m201-style 8-phase pair schedule ----------------
// Quadrants = (m-half x n-half) with FULL K=64 per phase; LDS slots [128][64]
// full-K with 3-bit XOR chunk swizzle (both-sides); JIT half-tile staging:
// p2:B(t+2) p4:A(t+2) p6:B(t+3) p8:A(t+3); vmcnt(8) at p4/p8; pure 16-MFMA
// bursts after lgkmcnt(0)+sched_barrier(0) (rule #18) with setprio (T5).
// __launch_bounds__(512,1): ~230 live VGPRs, no spill; LDS already caps at
// 1 block/CU so occupancy is unchanged vs (512,2).
// grid = 512: XCD x <-> expert x; persistent over expert's item space.
// KIND 0: gu GEMM, gate/up paired cols, fused silu*up -> inter (bf16)
// KIND 1: down GEMM, direct scattered f32 stores
template <int KTOT, int KIND>
__device__ __forceinline__ void gemm8_body(
    const u16* __restrict__ A, const u16* __restrict__ Bmat, void* __restrict__ outp,
    const int* __restrict__ offcnt, const int* __restrict__ order, int T) {
  constexpr int NK = KTOT / 64;  // 32 (gu) / 16 (down)
  constexpr int NPAIR = NK / 2;
  constexpr int ASTR = (KIND == 0) ? H_DIM : EI_DIM;
  constexpr int BSTR = ASTR;
  constexpr size_t BEXP = (size_t)2048 * BSTR;
  // [buf][half][128 rows x 64 k] bf16, full-K slots
  __shared__ u16 As[2][2][8192];
  __shared__ u16 Bs[2][2][8192];

  int nwg = gridDim.x;  // 512
  int bid = blockIdx.x;
  int bx = (bid & 7) * (nwg >> 3) + (bid >> 3);  // XCD-chunked, bijective
  int e = bx >> 6;
  int s0 = bx & 63;
  int off = offcnt[e], cnt = offcnt[8 + e];
  const u16* Be = Bmat + (size_t)e * BEXP;

  int tid = threadIdx.x, w = tid >> 6, l = tid & 63;
  int wm = w >> 2, wn = w & 3, lr = l & 15, lg = l >> 4;
  // read-side swizzled chunk offsets (u16 elems) for ks=0/1
  int cks[2];
  cks[0] = ((lg) ^ (lr & 7)) * 8;
  cks[1] = ((4 + lg) ^ (lr & 7)) * 8;
  // staging lane geometry: row-in-64-subblock + swizzled source chunk
  int srow = w * 8 + (l >> 3);          // 0..63
  int scol = ((l & 7) ^ (l >> 3)) * 8;  // source elem offset

#pragma unroll 1
  for (int it = s0; it < 512; it += 64) {
    int mt = it >> 3, nt = it & 7;
    if (mt * 256 >= cnt) continue;

    const u16* aS[2][2];
    const u16* bS[2][2];
#pragma unroll
    for (int h = 0; h < 2; ++h)
#pragma unroll
      for (int si = 0; si < 2; ++si) {
        int r = h * 128 + si * 64 + srow;  // tile row / tile col 0..255
        int grow = min(off + mt * 256 + r, T - 1);
        aS[h][si] = A + (size_t)grow * ASTR + scol;
        int n;
        if (KIND == 0) {
          int q = r >> 4, rr = r & 15;  // pair gate/up at 16-col granularity
          n = ((q & 2) ? EI_DIM : 0) + nt * 128 + ((q >> 2) << 5) + ((q & 1) << 4) + rr;
        } else {
          n = nt * 256 + r;
        }
        bS[h][si] = Be + (size_t)n * BSTR + scol;
      }

    auto stA = [&](int kt, int buf) {  // both halves: 4 loads
#pragma unroll
      for (int h = 0; h < 2; ++h)
#pragma unroll
        for (int si = 0; si < 2; ++si)
          load_lds16(aS[h][si] + kt * 64, &As[buf][h][si * 4096 + w * 512]);
    };
    auto stB = [&](int kt, int buf) {
#pragma unroll
      for (int h = 0; h < 2; ++h)
#pragma unroll
        for (int si = 0; si < 2; ++si)
          load_lds16(bS[h][si] + kt * 64, &Bs[buf][h][si * 4096 + w * 512]);
    };

    short8 av[4][2], bv[4][2];
    auto RDAV = [&](auto BUF, auto MQ) {
      constexpr int buf = decltype(BUF)::value, mq = decltype(MQ)::value;
#pragma unroll
      for (int mm = 0; mm < 4; ++mm)
#pragma unroll
        for (int ks = 0; ks < 2; ++ks)
          av[mm][ks] =
              *(const short8*)&As[buf][wm][(mq * 64 + mm * 16 + lr) * 64 + cks[ks]];
    };
    auto RDBV = [&](auto BUF) {
      constexpr int buf = decltype(BUF)::value;
#pragma unroll
      for (int nn = 0; nn < 4; ++nn)
#pragma unroll
        for (int ks = 0; ks < 2; ++ks)
          bv[nn][ks] = *(const short8*)&Bs[buf][wn >> 1]
                           [((wn & 1) * 64 + nn * 16 + lr) * 64 + cks[ks]];
    };

    f32x4 acc[8][4];
#pragma unroll
    for (int m = 0; m < 8; ++m)
#pragma unroll
      for (int nn = 0; nn < 4; ++nn) acc[m][nn] = {0.f, 0.f, 0.f, 0.f};

    auto BURST = [&](auto MQ, auto NQ) {  // pure 16-MFMA burst
      constexpr int mq = decltype(MQ)::value, nq = decltype(NQ)::value;
      __builtin_amdgcn_s_setprio(1);
#pragma unroll
      for (int mm = 0; mm < 4; ++mm)
#pragma unroll
        for (int nn = 0; nn < 2; ++nn)
#pragma unroll
          for (int ks = 0; ks < 2; ++ks)
            acc[mq * 4 + mm][nq * 2 + nn] = __builtin_amdgcn_mfma_f32_16x16x32_bf16(
                av[mm][ks], bv[nq * 2 + nn][ks], acc[mq * 4 + mm][nq * 2 + nn], 0, 0, 0);
      __builtin_amdgcn_s_setprio(0);
    };

#define BAR __builtin_amdgcn_s_barrier()
#define LGKM0                                          \
  do {                                                 \
    asm volatile("s_waitcnt lgkmcnt(0)" ::: "memory"); \
    __builtin_amdgcn_sched_barrier(0);                 \
  } while (0)

    // protect LDS against previous item's readers (also drains counters)
    __syncthreads();

    // ---- prologue: A(T0),B(T0) then B(T1),A(T1); keep T1's 8 in flight ----
    stA(0, 0);
    stB(0, 0);
    stB(1, 1);
    stA(1, 1);
    asm volatile("s_waitcnt vmcnt(8)" ::: "memory");
    BAR;
    __builtin_amdgcn_sched_barrier(0);

    auto PAIR = [&](int t2, int t3, auto LASTC) {
      constexpr bool last = decltype(LASTC)::value;
      // p1: (mq0,nq0) on buf0 | reads av(mq0)+bv(all)
      RDAV(IC<0>{}, IC<0>{});
      RDBV(IC<0>{});
      BAR;
      LGKM0;
      BURST(IC<0>{}, IC<0>{});
      BAR;
      // p2: (mq0,nq1) | stage B(t2->buf0)  [B(buf0) free after p1]
      if constexpr (!last) stB(t2, 0);
      BAR;
      BURST(IC<0>{}, IC<1>{});
      BAR;
      // p3: (mq1,nq0) | reads av(mq1)
      RDAV(IC<0>{}, IC<1>{});
      BAR;
      LGKM0;
      BURST(IC<1>{}, IC<0>{});
      BAR;
      // p4: (mq1,nq1) | stage A(t2->buf0) [A(buf0) free after p3]; vmcnt
      if constexpr (!last) stA(t2, 0);
      BAR;
      BURST(IC<1>{}, IC<1>{});
      if constexpr (!last)
        asm volatile("s_waitcnt vmcnt(8)" ::: "memory");
      else
        asm volatile("s_waitcnt vmcnt(0)" ::: "memory");
      BAR;
      // p5: buf1 (mq0,nq0)
      RDAV(IC<1>{}, IC<0>{});
      RDBV(IC<1>{});
      BAR;
      LGKM0;
      BURST(IC<0>{}, IC<0>{});
      BAR;
      // p6: stage B(t3->buf1)
      if constexpr (!last) stB(t3, 1);
      BAR;
      BURST(IC<0>{}, IC<1>{});
      BAR;
      // p7
      RDAV(IC<1>{}, IC<1>{});
      BAR;
      LGKM0;
      BURST(IC<1>{}, IC<0>{});
      BAR;
      // p8: stage A(t3->buf1); vmcnt(8)
      if constexpr (!last) stA(t3, 1);
      BAR;
      BURST(IC<1>{}, IC<1>{});
      if constexpr (!last) asm volatile("s_waitcnt vmcnt(8)" ::: "memory");
      BAR;
    };

#pragma unroll 1
    for (int i = 0; i < NPAIR - 1; ++i) PAIR(2 * i + 2, 2 * i + 3, IC<0>{});
    PAIR(0, 0, IC<1>{});

#undef BAR
#undef LGKM0

    // ---- epilogue ----
    if (KIND == 0) {
      u16* inter = (u16*)outp;
#pragma unroll
      for (int m = 0; m < 8; ++m)
#pragma unroll
        for (int nn = 0; nn < 2; ++nn) {
          f32x4 g = acc[m][nn], u = acc[m][nn + 2];
          int icol = nt * 128 + wn * 32 + nn * 16 + lr;
#pragma unroll
          for (int j = 0; j < 4; ++j) {
            int r = wm * 128 + m * 16 + lg * 4 + j;
            int grow = mt * 256 + r;
            if (grow < cnt) {
              float gv = g[j];
              float val = (gv / (1.f + __expf(-gv))) * u[j];
              inter[(size_t)(off + grow) * EI_DIM + icol] = f2bf(val);
            }
          }
        }
    } else {
      float* out = (float*)outp;
#pragma unroll
      for (int m = 0; m < 8; ++m)
#pragma unroll
        for (int j = 0; j < 4; ++j) {
          int r = wm * 128 + m * 16 + lg * 4 + j;
          int grow = mt * 256 + r;
          if (grow < cnt) {
            float* orow = out + (size_t)order[off + grow] * H_DIM + nt * 256 + wn * 64 + lr;
#pragma unroll
            for (int nn = 0; nn < 4; ++nn) orow[nn * 16] = acc[m][nn][j];
          }
        }
    }
  }
}

__global__ __launch_bounds__(512, 1) void gemm_gu_kernel(
    const u16* __restrict__ A, const u16* __restrict__ Bmat, void* __restrict__ outp,
    const int* __restrict__ offcnt, int T) {
  gemm8_body<2048, 0>(A, Bmat, outp, offcnt, nullptr, T);
}

__global__ __launch_bounds__(512, 1) void gemm_down_kernel(
    const u16* __restrict__ A, const u16* __restrict__ Bmat, void* __restrict__ outp,
    const int* __restrict__ offcnt, const int* __restrict__ order, int T) {
  gemm8_body<1024, 1>(A, Bmat, outp, offcnt, order, T);
}

extern "C" void kernel_launch(void* const* d_in, const int* in_sizes, int n_in,
                              void* d_out, int out_size, void* d_ws, size_t ws_size,
                              hipStream_t stream) {
  const float* x = (const float*)d_in[0];
  const int* pid = (const int*)d_in[1];
  const float* gup = (const float*)d_in[2];
  const float* dwn = (const float*)d_in[3];
  float* out = (float*)d_out;

  const int T = in_sizes[1];  // 16384

  char* ws = (char*)d_ws;
  size_t o = 0;
  auto take = [&](size_t b) { size_t r = o; o += (b + 255) & ~(size_t)255; return r; };
  int* offcnt = (int*)(ws + take(32 * 4));
  int* order = (int*)(ws + take((size_t)T * 4));
  u16* xg = (u16*)(ws + take((size_t)T * H_DIM * 2));
  u16* wguT = (u16*)(ws + take((size_t)NEXP * 2048 * 2048 * 2));
  u16* wdT = (u16*)(ws + take((size_t)NEXP * 2048 * 1024 * 2));
  u16* inter = (u16*)(ws + take((size_t)T * EI_DIM * 2));

  route_kernel<<<1, 1024, 0, stream>>>(pid, offcnt, order, T);
  convert_kernel<<<8192 + 4096 + 2048, 256, 0, stream>>>(gup, dwn, x, order, wguT, wdT, xg);
  gemm_gu_kernel<<<512, 512, 0, stream>>>(xg, wguT, inter, offcnt, T);
  gemm_down_kernel<<<512, 512, 0, stream>>>(inter, wdT, out, offcnt, order, T);
}

// Round 17
// 333.827 us; speedup vs baseline: 1.0708x; 1.0708x over previous
//
#include <hip/hip_runtime.h>
#include <hip/hip_bf16.h>

typedef unsigned short u16;
typedef __attribute__((ext_vector_type(8))) short short8;
typedef __attribute__((ext_vector_type(8))) unsigned short u16x8;
typedef __attribute__((ext_vector_type(4))) float f32x4;

#define H_DIM 2048
#define EI_DIM 1024
#define NEXP 8

template <int V> struct IC { static constexpr int value = V; };

__device__ __forceinline__ u16 f2bf(float f) {
  __hip_bfloat16 h = __float2bfloat16(f);
  return __builtin_bit_cast(unsigned short, h);
}

__device__ __forceinline__ void load_lds16(const void* g, void* lds) {
  __builtin_amdgcn_global_load_lds(
      (const __attribute__((address_space(1))) unsigned int*)g,
      (__attribute__((address_space(3))) unsigned int*)lds, 16, 0, 0);
}

// ---------------- routing ----------------
__global__ void hist_kernel(const int* __restrict__ pid, int* __restrict__ hist) {
  int seg = blockIdx.x, lane = threadIdx.x;
  int eid = pid[seg * 64 + lane] & 7;
#pragma unroll
  for (int e = 0; e < NEXP; ++e) {
    unsigned long long m = __ballot(eid == e);
    if (lane == 0) hist[e * 256 + seg] = __popcll(m);
  }
}

__global__ void scan_kernel(const int* __restrict__ hist, int* __restrict__ base,
                            int* __restrict__ offcnt, int T) {
  __shared__ int lds[256];
  int tid = threadIdx.x;
  int v[8], s = 0;
#pragma unroll
  for (int j = 0; j < 8; ++j) { v[j] = hist[tid * 8 + j]; s += v[j]; }
  lds[tid] = s;
  __syncthreads();
  for (int d = 1; d < 256; d <<= 1) {
    int t = (tid >= d) ? lds[tid - d] : 0;
    __syncthreads();
    lds[tid] += t;
    __syncthreads();
  }
  int run = lds[tid] - s;
#pragma unroll
  for (int j = 0; j < 8; ++j) { base[tid * 8 + j] = run; run += v[j]; }
  __syncthreads();
  if (tid < NEXP) {
    int o = base[tid * 256];
    int nx = (tid < NEXP - 1) ? base[(tid + 1) * 256] : T;
    offcnt[tid] = o;
    offcnt[8 + tid] = nx - o;
  }
}

__global__ void rank_kernel(const int* __restrict__ pid, const int* __restrict__ base,
                            int* __restrict__ order) {
  int seg = blockIdx.x, lane = threadIdx.x;
  int t = seg * 64 + lane;
  int eid = pid[t] & 7;
  unsigned long long below = (1ull << lane) - 1ull;
#pragma unroll
  for (int e = 0; e < NEXP; ++e) {
    unsigned long long m = __ballot(eid == e);
    if (eid == e) {
      int r = __popcll(m & below);
      order[base[e * 256 + seg] + r] = t;
    }
  }
}

// ---------------- weight transpose + fp32->bf16 ----------------
__global__ __launch_bounds__(256) void transpose_bf16(const float* __restrict__ in,
                                                      u16* __restrict__ out, int R, int C) {
  __shared__ u16 tile[64][65];
  int nbr = R >> 6, nbc = C >> 6;
  int per_e = nbr * nbc;
  int bx = blockIdx.x;
  int e = bx / per_e, rem = bx % per_e;
  int tr = rem % nbr, tc = rem / nbr;
  const float* ine = in + (size_t)e * R * C;
  u16* oute = out + (size_t)e * R * C;
  int r0 = tr * 64, c0 = tc * 64;
  int tid = threadIdx.x;
  int lrow = tid >> 4, lc4 = (tid & 15) * 4;
#pragma unroll
  for (int p = 0; p < 4; ++p) {
    int rl = p * 16 + lrow;
    float4 v = *(const float4*)&ine[(size_t)(r0 + rl) * C + c0 + lc4];
    tile[rl][lc4 + 0] = f2bf(v.x);
    tile[rl][lc4 + 1] = f2bf(v.y);
    tile[rl][lc4 + 2] = f2bf(v.z);
    tile[rl][lc4 + 3] = f2bf(v.w);
  }
  __syncthreads();
#pragma unroll
  for (int q = 0; q < 16; ++q) {
    int idx = q * 256 + tid;
    int jr = idx >> 6, hc = idx & 63;
    oute[(size_t)(c0 + jr) * R + r0 + hc] = tile[hc][jr];
  }
}

// ---------------- gather + convert x ----------------
__global__ __launch_bounds__(256) void gather_x(const float* __restrict__ x,
                                                const int* __restrict__ order,
                                                u16* __restrict__ xg) {
  int g = blockIdx.x;
  int t = order[g];
  const float* src = x + (size_t)t * H_DIM;
  u16* dst = xg + (size_t)g * H_DIM;
  int c = threadIdx.x * 8;
  float4 a = *(const float4*)&src[c];
  float4 b = *(const float4*)&src[c + 4];
  u16x8 v;
  v[0] = f2bf(a.x); v[1] = f2bf(a.y); v[2] = f2bf(a.z); v[3] = f2bf(a.w);
  v[4] = f2bf(b.x); v[5] = f2bf(b.y); v[6] = f2bf(b.z); v[7] = f2bf(b.w);
  *(u16x8*)&dst[c] = v;
}

// ---------------- 256x256 8-phase GEMM body, reg-ping-pong pipelined ----------------
// grid = 512: XCD x <-> expert x (chunked swizzle); persistent over expert's item space.
// Fragment regs ping-pong (avA/avB, bvA/bvB); each phase's ds_reads issued one
// phase early into the idle set -> writeback overlaps MFMA (no WAR-on-register
// serialization with the in-flight MFMA cluster).
// KIND 0: gu GEMM, gate/up paired cols, fused silu*up -> inter (bf16)
// KIND 1: down GEMM, LDS-staged float4 scatter of fp32 rows to d_out via order[]
template <int KTOT, int KIND>
__device__ __forceinline__ void gemm8_body(
    const u16* __restrict__ A, const u16* __restrict__ Bmat, void* __restrict__ outp,
    const int* __restrict__ offcnt, const int* __restrict__ order, int T) {
  constexpr int NK = KTOT / 64;  // even, >= 4
  constexpr int ASTR = (KIND == 0) ? H_DIM : EI_DIM;
  constexpr int BSTR = ASTR;
  constexpr size_t BEXP = (size_t)2048 * BSTR;
  __shared__ u16 As[2][2][8192];
  __shared__ u16 Bs[2][2][8192];

  int nwg = gridDim.x;  // 512
  int bid = blockIdx.x;
  int bx = (bid & 7) * (nwg >> 3) + (bid >> 3);  // XCD-chunked, bijective
  int e = bx >> 6;                               // 64 slots per expert
  int s = bx & 63;
  int off = offcnt[e], cnt = offcnt[8 + e];
  const u16* Be = Bmat + (size_t)e * BEXP;

  int tid = threadIdx.x, w = tid >> 6, l = tid & 63;
  int wm = w >> 2, wn = w & 3, lr = l & 15, lg = l >> 4;
  int cidx = (lg ^ ((lr >> 1) & 3)) * 8;  // swizzled 8-elem chunk for ds_read
  int aRow0 = wm * 128 + lr;
  int bRow0 = wn * 64 + lr;
  int sr[2], sc[2];
#pragma unroll
  for (int j = 0; j < 2; ++j) {
    sr[j] = j * 128 + (tid >> 2);
    int c = tid & 3;
    sc[j] = (c ^ ((sr[j] >> 1) & 3)) * 8;
  }

#pragma unroll 1
  for (int it = s; it < 512; it += 64) {
    int mt = it >> 3, nt = it & 7;
    if (mt * 256 >= cnt) continue;

    const u16* aSrc[2];
    const u16* bSrc[2];
#pragma unroll
    for (int j = 0; j < 2; ++j) {
      int r = sr[j];
      int grow = min(off + mt * 256 + r, T - 1);
      aSrc[j] = A + (size_t)grow * ASTR + sc[j];
      int n;
      if (KIND == 0) {
        int q = r >> 4, rr = r & 15;  // pair gate/up at wave granularity
        n = ((q & 2) ? EI_DIM : 0) + nt * 128 + ((q >> 2) << 5) + ((q & 1) << 4) + rr;
      } else {
        n = nt * 256 + r;
      }
      bSrc[j] = Be + (size_t)n * BSTR + sc[j];
    }

    auto stageA = [&](int kt, int kh, int buf) {
#pragma unroll
      for (int j = 0; j < 2; ++j)
        load_lds16(aSrc[j] + kt * 64 + kh * 32, &As[buf][kh][j * 4096 + w * 512]);
    };
    auto stageB = [&](int kt, int kh, int buf) {
#pragma unroll
      for (int j = 0; j < 2; ++j)
        load_lds16(bSrc[j] + kt * 64 + kh * 32, &Bs[buf][kh][j * 4096 + w * 512]);
    };

    short8 avA[4], avB[4], bvA[4], bvB[4];
    auto RDA = [&](short8(&dst)[4], int buf, int kh, int h) {
#pragma unroll
      for (int mm = 0; mm < 4; ++mm)
        dst[mm] = *(const short8*)&As[buf][kh][(aRow0 + (h * 4 + mm) * 16) * 32 + cidx];
    };
    auto RDB = [&](short8(&dst)[4], int buf, int kh) {
#pragma unroll
      for (int nn = 0; nn < 4; ++nn)
        dst[nn] = *(const short8*)&Bs[buf][kh][(bRow0 + nn * 16) * 32 + cidx];
    };

    f32x4 acc[8][4];
#pragma unroll
    for (int m = 0; m < 8; ++m)
#pragma unroll
      for (int nn = 0; nn < 4; ++nn) acc[m][nn] = {0.f, 0.f, 0.f, 0.f};

    auto MF = [&](short8(&a)[4], short8(&b)[4], auto HC) {
      constexpr int h = decltype(HC)::value;
      __builtin_amdgcn_s_setprio(1);
#pragma unroll
      for (int mm = 0; mm < 4; ++mm)
#pragma unroll
        for (int nn = 0; nn < 4; ++nn)
          acc[h * 4 + mm][nn] =
              __builtin_amdgcn_mfma_f32_16x16x32_bf16(a[mm], b[nn], acc[h * 4 + mm][nn], 0, 0, 0);
      __builtin_amdgcn_s_setprio(0);
    };

    // protect LDS against previous iteration's readers
    __syncthreads();

    // ---- prologue: tile0 fully + tile1 {Bk0, Ak0, Bk1} ----
    stageA(0, 0, 0); stageB(0, 0, 0); stageA(0, 1, 0); stageB(0, 1, 0);
    stageB(1, 0, 1); stageA(1, 0, 1); stageB(1, 1, 1);
    asm volatile("s_waitcnt vmcnt(6)" ::: "memory");
    __builtin_amdgcn_s_barrier();
    __builtin_amdgcn_sched_barrier(0);

    // Per tile (buffer b fully landed at tile start):
    // p1: ST A(t+1,1,bn) | MF(avA,bvA,h0) | RD avB<-A[b][0]mh1      | BAR
    // p2: ST B(t+2,0,b)  | MF(avB,bvA,h1) | RD avA<-A[b][1]mh0, bvB | BAR
    // p3: ST A(t+2,0,b)  | MF(avA,bvB,h0) | vmcnt(4) | RD avB mh1   | BAR
    // p4: ST B(t+2,1,b)  | MF(avB,bvB,h1)                            | BAR
    auto TILE = [&](int t, auto BC) {
      constexpr int b = decltype(BC)::value;
      constexpr int bn = b ^ 1;
      RDA(avA, b, 0, 0);
      RDB(bvA, b, 0);
      // p1
      stageA(t + 1, 1, bn);
      MF(avA, bvA, IC<0>{});
      RDA(avB, b, 0, 1);
      __builtin_amdgcn_s_barrier();
      // p2
      stageB(t + 2, 0, b);
      MF(avB, bvA, IC<1>{});
      RDA(avA, b, 1, 0);
      RDB(bvB, b, 1);
      __builtin_amdgcn_s_barrier();
      // p3
      stageA(t + 2, 0, b);
      MF(avA, bvB, IC<0>{});
      asm volatile("s_waitcnt vmcnt(4)" ::: "memory");
      RDA(avB, b, 1, 1);
      __builtin_amdgcn_s_barrier();
      // p4
      stageB(t + 2, 1, b);
      MF(avB, bvB, IC<1>{});
      __builtin_amdgcn_s_barrier();
    };

#pragma unroll 1
    for (int t = 0; t < NK - 3; t += 2) {
      TILE(t, IC<0>{});
      TILE(t + 1, IC<1>{});
    }

    // ---- tail: tile NK-2 (buf0; stages only A(NK-1,k1)); drain; tile NK-1 (buf1) ----
    {
      RDA(avA, 0, 0, 0);
      RDB(bvA, 0, 0);
      stageA(NK - 1, 1, 1);
      MF(avA, bvA, IC<0>{});
      RDA(avB, 0, 0, 1);
      __builtin_amdgcn_s_barrier();
      MF(avB, bvA, IC<1>{});
      RDA(avA, 0, 1, 0);
      RDB(bvB, 0, 1);
      __builtin_amdgcn_s_barrier();
      MF(avA, bvB, IC<0>{});
      asm volatile("s_waitcnt vmcnt(0)" ::: "memory");
      RDA(avB, 0, 1, 1);
      __builtin_amdgcn_s_barrier();
      MF(avB, bvB, IC<1>{});
      __builtin_amdgcn_s_barrier();
      // tile NK-1: no stages, straightline
      RDA(avA, 1, 0, 0);
      RDB(bvA, 1, 0);
      MF(avA, bvA, IC<0>{});
      RDA(avB, 1, 0, 1);
      MF(avB, bvA, IC<1>{});
      RDA(avA, 1, 1, 0);
      RDB(bvB, 1, 1);
      MF(avA, bvB, IC<0>{});
      RDA(avB, 1, 1, 1);
      MF(avB, bvB, IC<1>{});
    }

    // ---- epilogue ----
    if (KIND == 0) {
      u16* inter = (u16*)outp;
#pragma unroll
      for (int m = 0; m < 8; ++m)
#pragma unroll
        for (int nn = 0; nn < 2; ++nn) {
          f32x4 g = acc[m][nn], u = acc[m][nn + 2];
          int icol = nt * 128 + wn * 32 + nn * 16 + lr;
#pragma unroll
          for (int j = 0; j < 4; ++j) {
            int r = wm * 128 + m * 16 + lg * 4 + j;
            int grow = mt * 256 + r;
            if (grow < cnt) {
              float gv = g[j];
              float val = (gv / (1.f + __expf(-gv))) * u[j];
              inter[(size_t)(off + grow) * EI_DIM + icol] = f2bf(val);
            }
          }
        }
    } else {
      // LDS-staged float4 scatter: chunk = 32 rows x 256 cols f32 (32 KB in As)
      float* out = (float*)outp;
      float* lf = (float*)&As[0][0][0];
#pragma unroll
      for (int m = 0; m < 8; ++m) {
        __syncthreads();
#pragma unroll
        for (int nn = 0; nn < 4; ++nn)
#pragma unroll
          for (int j = 0; j < 4; ++j)
            lf[(wm * 16 + lg * 4 + j) * 256 + wn * 64 + nn * 16 + lr] = acc[m][nn][j];
        __syncthreads();
#pragma unroll
        for (int k = 0; k < 4; ++k) {
          int idx = tid + k * 512;
          int rl = idx >> 6, c4 = idx & 63;
          int grow = mt * 256 + (rl >> 4) * 128 + m * 16 + (rl & 15);
          if (grow < cnt) {
            int tt = order[off + grow];
            *(float4*)&out[(size_t)tt * H_DIM + nt * 256 + c4 * 4] =
                *(const float4*)&lf[rl * 256 + c4 * 4];
          }
        }
      }
    }
  }
}

__global__ __launch_bounds__(512, 2) void gemm_gu_kernel(
    const u16* __restrict__ A, const u16* __restrict__ Bmat, void* __restrict__ outp,
    const int* __restrict__ offcnt, int T) {
  gemm8_body<2048, 0>(A, Bmat, outp, offcnt, nullptr, T);
}

__global__ __launch_bounds__(512, 2) void gemm_down_kernel(
    const u16* __restrict__ A, const u16* __restrict__ Bmat, void* __restrict__ outp,
    const int* __restrict__ offcnt, const int* __restrict__ order, int T) {
  gemm8_body<1024, 1>(A, Bmat, outp, offcnt, order, T);
}

extern "C" void kernel_launch(void* const* d_in, const int* in_sizes, int n_in,
                              void* d_out, int out_size, void* d_ws, size_t ws_size,
                              hipStream_t stream) {
  const float* x = (const float*)d_in[0];
  const int* pid = (const int*)d_in[1];
  const float* gup = (const float*)d_in[2];
  const float* dwn = (const float*)d_in[3];
  float* out = (float*)d_out;

  const int T = in_sizes[1];  // 16384

  char* ws = (char*)d_ws;
  size_t o = 0;
  auto take = [&](size_t b) { size_t r = o; o += (b + 255) & ~(size_t)255; return r; };
  int* offcnt = (int*)(ws + take(32 * 4));
  int* hist = (int*)(ws + take(2048 * 4));
  int* base = (int*)(ws + take(2052 * 4));
  int* order = (int*)(ws + take((size_t)T * 4));
  u16* xg = (u16*)(ws + take((size_t)T * H_DIM * 2));
  u16* wguT = (u16*)(ws + take((size_t)NEXP * 2048 * 2048 * 2));
  u16* wdT = (u16*)(ws + take((size_t)NEXP * 2048 * 1024 * 2));
  u16* inter = (u16*)(ws + take((size_t)T * EI_DIM * 2));

  hist_kernel<<<T / 64, 64, 0, stream>>>(pid, hist);
  scan_kernel<<<1, 256, 0, stream>>>(hist, base, offcnt, T);
  rank_kernel<<<T / 64, 64, 0, stream>>>(pid, base, order);
  transpose_bf16<<<NEXP * 32 * 32, 256, 0, stream>>>(gup, wguT, 2048, 2048);
  transpose_bf16<<<NEXP * 16 * 32, 256, 0, stream>>>(dwn, wdT, 1024, 2048);
  gather_x<<<T, 256, 0, stream>>>(x, order, xg);

  gemm_gu_kernel<<<512, 512, 0, stream>>>(xg, wguT, inter, offcnt, T);
  gemm_down_kernel<<<512, 512, 0, stream>>>(inter, wdT, out, offcnt, order, T);
}